// Round 5
// baseline (286.786 us; speedup 1.0000x reference)
//
#include <hip/hip_runtime.h>
#include <hip/hip_bf16.h>
#include <hip/hip_cooperative_groups.h>

namespace cg = cooperative_groups;

// Problem constants (fixed by the reference): B=16, V=8192, N=2048, H=128, C_OUT=7
#define B_GR   16
#define V_PTS  8192
#define N_RES  2048
#define H_DIM  128
#define C_OUT  7
#define SEGS   16                    // pool phase: residue segments per graph

// vertex decomposition (shared by fused + fallback argmin)
#define VPT    8                     // vertices per thread (8 independent FMA chains)
#define VBLK   (256 * VPT)           // 2048 vertices per block
#define VBLKS  (V_PTS / VBLK)        // 4 vertex-blocks per graph

// ---------------------------------------------------------------------------
// Bit-exact distance (identical to reference fp32 op sequence):
//   d = fadd( fma(-2, dot, vsq), csq ), dot = fadd(fadd(x*cx, y*cy), z*cz)
// fma(-2,dot,vsq) == RN(vsq - 2*dot) exactly (scaling by 2 is exact).
// Partial argmins merged via atomicMin on packed
// (monotone-flipped dist bits << 32) | global_idx — ties pick smaller index
// (np.argmin first-occurrence); d == -0.0 impossible since csq >= +0.
// ---------------------------------------------------------------------------

union ShMem {
    float4 sc[N_RES / 4];                                 // phase 1: up to 8 KB (NS=4)
    struct { float msk[N_RES]; float4 red[8][32]; } pool; // phase 2: 12 KB
    struct { float pooled[H_DIM]; float h1[H_DIM]; } mlp; // phase 3: 1 KB
};

template <int NS>   // residue splits per graph; grid = B_GR * VBLKS * NS
__global__ __launch_bounds__(256, 2) void k_fused(const float* __restrict__ verts,
                                                  const float* __restrict__ coords,
                                                  const float* __restrict__ feats,
                                                  const float* __restrict__ W1,
                                                  const float* __restrict__ b1,
                                                  const float* __restrict__ W2,
                                                  const float* __restrict__ b2,
                                                  float* __restrict__ out,
                                                  unsigned long long* __restrict__ mi64,
                                                  float* __restrict__ partial) {
    constexpr int NL = N_RES / NS;                        // residues per block
    cg::grid_group grid = cg::this_grid();
    __shared__ ShMem u;

    // ---------------- phase 0: init mi64 (replaces memset node) ----------------
    for (unsigned int gid = blockIdx.x * 256u + threadIdx.x;
         gid < B_GR * V_PTS; gid += gridDim.x * 256u)
        mi64[gid] = ~0ULL;
    grid.sync();

    // ---------------- phase 1: partial argmin ----------------
    {
        const int b  = blockIdx.x / (VBLKS * NS);
        const int r  = blockIdx.x % (VBLKS * NS);
        const int vb = r / NS;
        const int ns = r % NS;

        const float* cbase = coords + ((size_t)b * N_RES + ns * NL) * 3;
        for (int i = threadIdx.x; i < NL; i += 256) {
            float x = cbase[i * 3 + 0];
            float y = cbase[i * 3 + 1];
            float z = cbase[i * 3 + 2];
            float csq = __fadd_rn(__fadd_rn(__fmul_rn(x, x), __fmul_rn(y, y)), __fmul_rn(z, z));
            u.sc[i] = make_float4(x, y, z, csq);
        }
        __syncthreads();

        const int vbase = vb * VBLK + threadIdx.x;
        const float* vp = verts + (size_t)b * V_PTS * 3;

        float vx[VPT], vy[VPT], vz[VPT], vsq[VPT], best[VPT];
        int bi[VPT];
#pragma unroll
        for (int k = 0; k < VPT; ++k) {
            const int v = vbase + k * 256;
            vx[k] = vp[v * 3 + 0];
            vy[k] = vp[v * 3 + 1];
            vz[k] = vp[v * 3 + 2];
            vsq[k] = __fadd_rn(__fadd_rn(__fmul_rn(vx[k], vx[k]), __fmul_rn(vy[k], vy[k])),
                               __fmul_rn(vz[k], vz[k]));
            best[k] = 3.402823466e+38f;
            bi[k] = 0;
        }

#pragma unroll 2
        for (int n = 0; n < NL; ++n) {
            const float4 c = u.sc[n];
#pragma unroll
            for (int k = 0; k < VPT; ++k) {
                float dot = __fadd_rn(__fadd_rn(__fmul_rn(vx[k], c.x), __fmul_rn(vy[k], c.y)),
                                      __fmul_rn(vz[k], c.z));
                float d = __fadd_rn(fmaf(-2.0f, dot, vsq[k]), c.w);
                bool m = d < best[k];                     // strict <: first index wins
                best[k] = m ? d : best[k];
                bi[k]   = m ? n : bi[k];
            }
        }

#pragma unroll
        for (int k = 0; k < VPT; ++k) {
            unsigned int bits = __float_as_uint(best[k]);
            unsigned int key  = bits ^ (unsigned int)(((int)bits >> 31) | 0x80000000);
            unsigned long long packed =
                ((unsigned long long)key << 32) | (unsigned int)(ns * NL + bi[k]);
            atomicMin(&mi64[(size_t)b * V_PTS + vbase + k * 256], packed);
        }
    }
    grid.sync();

    // ---------------- phase 2: hit-mask pool (blocks 0..255) ----------------
    if (blockIdx.x < B_GR * SEGS) {
        const int b   = blockIdx.x >> 4;
        const int seg = blockIdx.x & (SEGS - 1);

        for (int i = threadIdx.x; i < N_RES; i += 256) u.pool.msk[i] = 0.0f;
        __syncthreads();

        const unsigned long long* mb = mi64 + (size_t)b * V_PTS;
        for (int v = threadIdx.x; v < V_PTS; v += 256)
            u.pool.msk[(unsigned int)mb[v]] = 1.0f;       // race benign: all write 1
        __syncthreads();

        const int q = threadIdx.x & 31;                   // float4 column (h = 4q..4q+3)
        const int s = threadIdx.x >> 5;                   // n-slice 0..7
        const int n0 = seg * (N_RES / SEGS);
        const float4* fb4 = (const float4*)(feats + ((size_t)b * N_RES + n0) * H_DIM);

        float4 acc = make_float4(0.f, 0.f, 0.f, 0.f);
#pragma unroll
        for (int n = 0; n < N_RES / SEGS / 8; ++n) {
            const int nn = s + n * 8;
            const float m = u.pool.msk[n0 + nn];
            const float4 f = fb4[(size_t)nn * 32 + q];
            acc.x = fmaf(f.x, m, acc.x);
            acc.y = fmaf(f.y, m, acc.y);
            acc.z = fmaf(f.z, m, acc.z);
            acc.w = fmaf(f.w, m, acc.w);
        }
        u.pool.red[s][q] = acc;
        __syncthreads();

        if (s == 0) {
            float4 t = acc;
#pragma unroll
            for (int i = 1; i < 8; ++i) {
                t.x += u.pool.red[i][q].x; t.y += u.pool.red[i][q].y;
                t.z += u.pool.red[i][q].z; t.w += u.pool.red[i][q].w;
            }
            ((float4*)partial)[((size_t)b * SEGS + seg) * 32 + q] = t;
        }
    }
    grid.sync();

    // ---------------- phase 3: MLP head (blocks 0..15) ----------------
    if (blockIdx.x < B_GR) {
        const int b = blockIdx.x;
        const int j = threadIdx.x;

        if (j < H_DIM) {
            float s = 0.0f;
#pragma unroll
            for (int g = 0; g < SEGS; ++g)
                s += partial[((size_t)b * SEGS + g) * H_DIM + j];
            u.mlp.pooled[j] = s;
        }
        __syncthreads();

        if (j < H_DIM) {
            float acc = b1[j];
#pragma unroll 8
            for (int hh = 0; hh < H_DIM; ++hh)
                acc = fmaf(u.mlp.pooled[hh], W1[hh * H_DIM + j], acc);
            u.mlp.h1[j] = fmaxf(acc, 0.0f);
        }
        __syncthreads();

        if (j < C_OUT) {
            float o = b2[j];
#pragma unroll 8
            for (int hh = 0; hh < H_DIM; ++hh)
                o = fmaf(u.mlp.h1[hh], W2[hh * C_OUT + j], o);
            out[(size_t)b * C_OUT + j] = o;
        }
    }
}

// ===========================================================================
// Fallback path (known-good R3 structure, 150 us): memset + 3 kernels.
// ===========================================================================
#define FB_NSPLIT 16
#define FB_NL     (N_RES / FB_NSPLIT)   // 128

__global__ __launch_bounds__(256, 4) void k_argmin_fb(const float* __restrict__ verts,
                                                      const float* __restrict__ coords,
                                                      unsigned long long* __restrict__ mi64) {
    __shared__ float4 sc[FB_NL];
    const int b  = blockIdx.x / (VBLKS * FB_NSPLIT);
    const int r  = blockIdx.x % (VBLKS * FB_NSPLIT);
    const int vb = r / FB_NSPLIT;
    const int ns = r % FB_NSPLIT;

    const float* cbase = coords + ((size_t)b * N_RES + ns * FB_NL) * 3;
    if (threadIdx.x < FB_NL) {
        const int i = threadIdx.x;
        float x = cbase[i * 3 + 0];
        float y = cbase[i * 3 + 1];
        float z = cbase[i * 3 + 2];
        float csq = __fadd_rn(__fadd_rn(__fmul_rn(x, x), __fmul_rn(y, y)), __fmul_rn(z, z));
        sc[i] = make_float4(x, y, z, csq);
    }
    __syncthreads();

    const int vbase = vb * VBLK + threadIdx.x;
    const float* vp = verts + (size_t)b * V_PTS * 3;

    float vx[VPT], vy[VPT], vz[VPT], vsq[VPT], best[VPT];
    int bi[VPT];
#pragma unroll
    for (int k = 0; k < VPT; ++k) {
        const int v = vbase + k * 256;
        vx[k] = vp[v * 3 + 0];
        vy[k] = vp[v * 3 + 1];
        vz[k] = vp[v * 3 + 2];
        vsq[k] = __fadd_rn(__fadd_rn(__fmul_rn(vx[k], vx[k]), __fmul_rn(vy[k], vy[k])),
                           __fmul_rn(vz[k], vz[k]));
        best[k] = 3.402823466e+38f;
        bi[k] = 0;
    }

#pragma unroll 2
    for (int n = 0; n < FB_NL; ++n) {
        const float4 c = sc[n];
#pragma unroll
        for (int k = 0; k < VPT; ++k) {
            float dot = __fadd_rn(__fadd_rn(__fmul_rn(vx[k], c.x), __fmul_rn(vy[k], c.y)),
                                  __fmul_rn(vz[k], c.z));
            float d = __fadd_rn(fmaf(-2.0f, dot, vsq[k]), c.w);
            bool m = d < best[k];
            best[k] = m ? d : best[k];
            bi[k]   = m ? n : bi[k];
        }
    }

#pragma unroll
    for (int k = 0; k < VPT; ++k) {
        unsigned int bits = __float_as_uint(best[k]);
        unsigned int key  = bits ^ (unsigned int)(((int)bits >> 31) | 0x80000000);
        unsigned long long packed =
            ((unsigned long long)key << 32) | (unsigned int)(ns * FB_NL + bi[k]);
        atomicMin(&mi64[(size_t)b * V_PTS + vbase + k * 256], packed);
    }
}

__global__ __launch_bounds__(256) void k_pool_fb(const unsigned long long* __restrict__ mi64,
                                                 const float* __restrict__ feats,
                                                 float* __restrict__ partial) {
    __shared__ float msk[N_RES];
    __shared__ float4 red[8][32];
    const int b   = blockIdx.x >> 4;
    const int seg = blockIdx.x & (SEGS - 1);

    for (int i = threadIdx.x; i < N_RES; i += 256) msk[i] = 0.0f;
    __syncthreads();

    const unsigned long long* mb = mi64 + (size_t)b * V_PTS;
    for (int v = threadIdx.x; v < V_PTS; v += 256)
        msk[(unsigned int)mb[v]] = 1.0f;
    __syncthreads();

    const int q = threadIdx.x & 31;
    const int s = threadIdx.x >> 5;
    const int n0 = seg * (N_RES / SEGS);
    const float4* fb4 = (const float4*)(feats + ((size_t)b * N_RES + n0) * H_DIM);

    float4 acc = make_float4(0.f, 0.f, 0.f, 0.f);
#pragma unroll
    for (int n = 0; n < N_RES / SEGS / 8; ++n) {
        const int nn = s + n * 8;
        const float m = msk[n0 + nn];
        const float4 f = fb4[(size_t)nn * 32 + q];
        acc.x = fmaf(f.x, m, acc.x);
        acc.y = fmaf(f.y, m, acc.y);
        acc.z = fmaf(f.z, m, acc.z);
        acc.w = fmaf(f.w, m, acc.w);
    }
    red[s][q] = acc;
    __syncthreads();

    if (s == 0) {
        float4 t = acc;
#pragma unroll
        for (int i = 1; i < 8; ++i) {
            t.x += red[i][q].x; t.y += red[i][q].y;
            t.z += red[i][q].z; t.w += red[i][q].w;
        }
        ((float4*)partial)[((size_t)b * SEGS + seg) * 32 + q] = t;
    }
}

__global__ __launch_bounds__(128) void k_mlp_fb(const float* __restrict__ partial,
                                                const float* __restrict__ W1,
                                                const float* __restrict__ b1,
                                                const float* __restrict__ W2,
                                                const float* __restrict__ b2,
                                                float* __restrict__ out) {
    __shared__ float pooled[H_DIM];
    __shared__ float h1[H_DIM];
    const int b = blockIdx.x;
    const int j = threadIdx.x;

    float s = 0.0f;
#pragma unroll
    for (int g = 0; g < SEGS; ++g)
        s += partial[((size_t)b * SEGS + g) * H_DIM + j];
    pooled[j] = s;
    __syncthreads();

    float acc = b1[j];
#pragma unroll 8
    for (int hh = 0; hh < H_DIM; ++hh)
        acc = fmaf(pooled[hh], W1[hh * H_DIM + j], acc);
    h1[j] = fmaxf(acc, 0.0f);
    __syncthreads();

    if (j < C_OUT) {
        float o = b2[j];
#pragma unroll 8
        for (int hh = 0; hh < H_DIM; ++hh)
            o = fmaf(h1[hh], W2[hh * C_OUT + j], o);
        out[(size_t)b * C_OUT + j] = o;
    }
}

extern "C" void kernel_launch(void* const* d_in, const int* in_sizes, int n_in,
                              void* d_out, int out_size, void* d_ws, size_t ws_size,
                              hipStream_t stream) {
    const float* verts  = (const float*)d_in[0];   // [B,V,3]
    const float* coords = (const float*)d_in[1];   // [B,N,3]
    const float* feats  = (const float*)d_in[2];   // [B,N,H]
    const float* W1     = (const float*)d_in[3];   // [H,H]
    const float* b1     = (const float*)d_in[4];   // [H]
    const float* W2     = (const float*)d_in[5];   // [H,C_OUT]
    const float* b2     = (const float*)d_in[6];   // [C_OUT]
    float* out = (float*)d_out;                    // [B,C_OUT]

    unsigned long long* mi64 = (unsigned long long*)d_ws;                 // B*V u64 = 1 MB
    float* partial = (float*)((char*)d_ws + (size_t)B_GR * V_PTS * 8);    // B*SEGS*H = 128 KB

    void* args[] = { (void*)&verts, (void*)&coords, (void*)&feats, (void*)&W1,
                     (void*)&b1, (void*)&W2, (void*)&b2, (void*)&out,
                     (void*)&mi64, (void*)&partial };

    // Try cooperative at 512 blocks (2 blocks/CU), then 256 (1 block/CU).
    // Each attempt's decision is deterministic per environment -> same work
    // every call. On failure, clear the error and fall back.
    hipError_t e = hipLaunchCooperativeKernel((const void*)k_fused<8>,
                                              dim3(B_GR * VBLKS * 8), dim3(256),
                                              args, 0, stream);
    if (e != hipSuccess) {
        (void)hipGetLastError();
        e = hipLaunchCooperativeKernel((const void*)k_fused<4>,
                                       dim3(B_GR * VBLKS * 4), dim3(256),
                                       args, 0, stream);
    }
    if (e != hipSuccess) {
        (void)hipGetLastError();
        // known-good 4-node fallback (R3 structure)
        hipMemsetAsync(mi64, 0xFF, (size_t)B_GR * V_PTS * 8, stream);
        k_argmin_fb<<<B_GR * VBLKS * FB_NSPLIT, 256, 0, stream>>>(verts, coords, mi64);
        k_pool_fb  <<<B_GR * SEGS,              256, 0, stream>>>(mi64, feats, partial);
        k_mlp_fb   <<<B_GR,                     128, 0, stream>>>(partial, W1, b1, W2, b2, out);
    }
}

// Round 6
// 153.508 us; speedup vs baseline: 1.8682x; 1.8682x over previous
//
#include <hip/hip_runtime.h>
#include <hip/hip_bf16.h>

// Problem constants (fixed by the reference): B=16, V=8192, N=2048, H=128, C_OUT=7
#define B_GR   16
#define V_PTS  8192
#define N_RES  2048
#define H_DIM  128
#define C_OUT  7
#define SEGS   16                    // pool kernel: residue segments per graph

// argmin decomposition
// R5 lesson: total-vs-kernel gap is a FIXED ~85us harness overhead, not
// per-node; cooperative grid.sync costs ~40us each on gfx950 (XCD L2 flush).
// So: multi-kernel structure, minimize kernel-sum only.
#define NSPLIT 16                    // residue splits per graph
#define NL     (N_RES / NSPLIT)      // 128 residues per block
#define VPT    4                     // vertices per thread (4 independent chains)
#define VBLK   (256 * VPT)           // 1024 vertices per block
#define VBLKS  (V_PTS / VBLK)        // 8 vertex-blocks per graph
// grid = B * VBLKS * NSPLIT = 16*8*16 = 2048 blocks -> 8 blocks/CU, 32 waves/CU

// ---------------------------------------------------------------------------
// Kernel 1: partial nearest-residue argmin over a 128-residue slice, 4
// vertices per thread. Bit-exact replication of the reference fp32 sequence:
//   d = fadd( fma(-2, dot, vsq), csq ),  dot = fadd(fadd(x*cx, y*cy), z*cz)
// (fma(-2,dot,vsq) == RN(vsq - 2*dot) exactly since scaling by 2 is exact.)
// Partials merged across splits with atomicMin on packed
// (monotone-flipped dist bits << 32) | global_idx — equal dists pick the
// smaller index, matching np.argmin first-occurrence. d == -0.0 impossible
// (csq >= +0), so the flip transform is a strict order-embedding.
// ---------------------------------------------------------------------------
__global__ __launch_bounds__(256, 8) void k_argmin(const float* __restrict__ verts,
                                                   const float* __restrict__ coords,
                                                   unsigned long long* __restrict__ mi64) {
    __shared__ float4 sc[NL];                          // 2 KB
    const int b  = blockIdx.x / (VBLKS * NSPLIT);
    const int r  = blockIdx.x % (VBLKS * NSPLIT);
    const int vb = r / NSPLIT;
    const int ns = r % NSPLIT;

    const float* cbase = coords + ((size_t)b * N_RES + ns * NL) * 3;
    if (threadIdx.x < NL) {
        const int i = threadIdx.x;
        float x = cbase[i * 3 + 0];
        float y = cbase[i * 3 + 1];
        float z = cbase[i * 3 + 2];
        float csq = __fadd_rn(__fadd_rn(__fmul_rn(x, x), __fmul_rn(y, y)), __fmul_rn(z, z));
        sc[i] = make_float4(x, y, z, csq);
    }
    __syncthreads();

    const int vbase = vb * VBLK + threadIdx.x;         // vertex index within graph
    const float* vp = verts + (size_t)b * V_PTS * 3;

    float vx[VPT], vy[VPT], vz[VPT], vsq[VPT], best[VPT];
    int bi[VPT];
#pragma unroll
    for (int k = 0; k < VPT; ++k) {
        const int v = vbase + k * 256;
        vx[k] = vp[v * 3 + 0];
        vy[k] = vp[v * 3 + 1];
        vz[k] = vp[v * 3 + 2];
        vsq[k] = __fadd_rn(__fadd_rn(__fmul_rn(vx[k], vx[k]), __fmul_rn(vy[k], vy[k])),
                           __fmul_rn(vz[k], vz[k]));
        best[k] = 3.402823466e+38f;
        bi[k] = 0;
    }

    // unroll 2: n stays a uniform (SGPR) operand for the index cndmask.
#pragma unroll 2
    for (int n = 0; n < NL; ++n) {
        const float4 c = sc[n];
#pragma unroll
        for (int k = 0; k < VPT; ++k) {
            float dot = __fadd_rn(__fadd_rn(__fmul_rn(vx[k], c.x), __fmul_rn(vy[k], c.y)),
                                  __fmul_rn(vz[k], c.z));
            float d = __fadd_rn(fmaf(-2.0f, dot, vsq[k]), c.w);
            bool m = d < best[k];                      // strict <: first index wins
            best[k] = m ? d : best[k];
            bi[k]   = m ? n : bi[k];
        }
    }

#pragma unroll
    for (int k = 0; k < VPT; ++k) {
        unsigned int bits = __float_as_uint(best[k]);
        unsigned int key  = bits ^ (unsigned int)(((int)bits >> 31) | 0x80000000);
        unsigned long long packed =
            ((unsigned long long)key << 32) | (unsigned int)(ns * NL + bi[k]);
        atomicMin(&mi64[(size_t)b * V_PTS + vbase + k * 256], packed);
    }
}

// ---------------------------------------------------------------------------
// Kernel 2: rebuild per-graph hit mask in LDS from packed argmin (low 32 bits
// = index), masked-sum a 128-residue slice of feats with float4 loads.
// Grid: B*SEGS = 256 blocks, 256 threads.
// ---------------------------------------------------------------------------
__global__ __launch_bounds__(256) void k_pool(const unsigned long long* __restrict__ mi64,
                                              const float* __restrict__ feats,
                                              float* __restrict__ partial) {
    __shared__ float msk[N_RES];                        // 8 KB
    __shared__ float4 red[8][32];
    const int b   = blockIdx.x >> 4;
    const int seg = blockIdx.x & (SEGS - 1);

    for (int i = threadIdx.x; i < N_RES; i += 256) msk[i] = 0.0f;
    __syncthreads();

    const unsigned long long* mb = mi64 + (size_t)b * V_PTS;
    for (int v = threadIdx.x; v < V_PTS; v += 256)
        msk[(unsigned int)mb[v]] = 1.0f;                // race benign: all write 1
    __syncthreads();

    const int q = threadIdx.x & 31;                     // float4 column (h = 4q..4q+3)
    const int s = threadIdx.x >> 5;                     // n-slice 0..7
    const int n0 = seg * (N_RES / SEGS);
    const float4* fb4 = (const float4*)(feats + ((size_t)b * N_RES + n0) * H_DIM);

    float4 acc = make_float4(0.f, 0.f, 0.f, 0.f);
#pragma unroll
    for (int n = 0; n < N_RES / SEGS / 8; ++n) {
        const int nn = s + n * 8;
        const float m = msk[n0 + nn];
        const float4 f = fb4[(size_t)nn * 32 + q];
        acc.x = fmaf(f.x, m, acc.x);
        acc.y = fmaf(f.y, m, acc.y);
        acc.z = fmaf(f.z, m, acc.z);
        acc.w = fmaf(f.w, m, acc.w);
    }
    red[s][q] = acc;
    __syncthreads();

    if (s == 0) {
        float4 t = acc;
#pragma unroll
        for (int i = 1; i < 8; ++i) {
            t.x += red[i][q].x; t.y += red[i][q].y;
            t.z += red[i][q].z; t.w += red[i][q].w;
        }
        ((float4*)partial)[((size_t)b * SEGS + seg) * 32 + q] = t;
    }
}

// ---------------------------------------------------------------------------
// Kernel 3: per-graph block — reduce 16 seg partials -> pooled[H], then
// relu(pooled@W1+b1)@W2+b2 -> out[b][7]. 16 blocks x 128 threads.
// ---------------------------------------------------------------------------
__global__ __launch_bounds__(128) void k_mlp(const float* __restrict__ partial,
                                             const float* __restrict__ W1,
                                             const float* __restrict__ b1,
                                             const float* __restrict__ W2,
                                             const float* __restrict__ b2,
                                             float* __restrict__ out) {
    __shared__ float pooled[H_DIM];
    __shared__ float h1[H_DIM];
    const int b = blockIdx.x;
    const int j = threadIdx.x;

    float s = 0.0f;
#pragma unroll
    for (int g = 0; g < SEGS; ++g)
        s += partial[((size_t)b * SEGS + g) * H_DIM + j];
    pooled[j] = s;
    __syncthreads();

    float acc = b1[j];
#pragma unroll 8
    for (int hh = 0; hh < H_DIM; ++hh)
        acc = fmaf(pooled[hh], W1[hh * H_DIM + j], acc);
    h1[j] = fmaxf(acc, 0.0f);
    __syncthreads();

    if (j < C_OUT) {
        float o = b2[j];
#pragma unroll 8
        for (int hh = 0; hh < H_DIM; ++hh)
            o = fmaf(h1[hh], W2[hh * C_OUT + j], o);
        out[(size_t)b * C_OUT + j] = o;
    }
}

extern "C" void kernel_launch(void* const* d_in, const int* in_sizes, int n_in,
                              void* d_out, int out_size, void* d_ws, size_t ws_size,
                              hipStream_t stream) {
    const float* verts  = (const float*)d_in[0];   // [B,V,3]
    const float* coords = (const float*)d_in[1];   // [B,N,3]
    const float* feats  = (const float*)d_in[2];   // [B,N,H]
    const float* W1     = (const float*)d_in[3];   // [H,H]
    const float* b1     = (const float*)d_in[4];   // [H]
    const float* W2     = (const float*)d_in[5];   // [H,C_OUT]
    const float* b2     = (const float*)d_in[6];   // [C_OUT]
    float* out = (float*)d_out;                    // [B,C_OUT]

    // workspace layout
    unsigned long long* mi64 = (unsigned long long*)d_ws;                 // B*V u64 = 1 MB
    float* partial = (float*)((char*)d_ws + (size_t)B_GR * V_PTS * 8);    // B*SEGS*H = 128 KB

    hipMemsetAsync(mi64, 0xFF, (size_t)B_GR * V_PTS * 8, stream);         // graph-legal memset node
    k_argmin<<<B_GR * VBLKS * NSPLIT, 256, 0, stream>>>(verts, coords, mi64);
    k_pool  <<<B_GR * SEGS,           256, 0, stream>>>(mi64, feats, partial);
    k_mlp   <<<B_GR,                  128, 0, stream>>>(partial, W1, b1, W2, b2, out);
}